// Round 4
// baseline (339.051 us; speedup 1.0000x reference)
//
#include <hip/hip_runtime.h>

// MHA fwd: B=2, S=2048, d=1024, H=16, hd=64. fp32 accum, bf16 MFMA compute.
// Split-K flash attention (2 splits) + merge. Dtype-adaptive input conversion.

typedef __bf16 bf16;
typedef __bf16 bf16x4 __attribute__((ext_vector_type(4)));
typedef __bf16 bf16x8 __attribute__((ext_vector_type(8)));
typedef float f32x4 __attribute__((ext_vector_type(4)));

#define DEV static __device__ __forceinline__

constexpr int D = 1024;
constexpr int NH = 16;
constexpr int HD = 64;
constexpr int B_ = 2;
constexpr int S_ = 2048;
constexpr size_t MAT = (size_t)D * D;        // 1,048,576
constexpr size_t XSZ = (size_t)B_ * S_ * D;  // 4,194,304

DEV void glds16(const bf16* g, bf16* l) {
  __builtin_amdgcn_global_load_lds(
      (__attribute__((address_space(1))) void*)g,
      (__attribute__((address_space(3))) void*)l, 16, 0, 0);
}

// ---------------- dtype detection ----------------
__global__ __launch_bounds__(256) void detect_k(const unsigned short* __restrict__ w,
                                                int* __restrict__ flag) {
  __shared__ int sbuf[256];
  const int tid = threadIdx.x;
  int cnt = 0;
  for (int i = tid; i < 8192; i += 256) {
    const unsigned e = (w[i] >> 7) & 0xFF;
    if (e >= 0x90) cnt++;
  }
  sbuf[tid] = cnt;
  __syncthreads();
  for (int s = 128; s > 0; s >>= 1) {
    if (tid < s) sbuf[tid] += sbuf[tid + s];
    __syncthreads();
  }
  if (tid == 0) flag[0] = (sbuf[0] > 32) ? 1 : 0;
}

// ---------------- input conversion (coalesced float4) ----------------
__global__ __launch_bounds__(256) void convert_x(const void* __restrict__ X0,
                                                 const void* __restrict__ X1,
                                                 const void* __restrict__ X2,
                                                 const int* __restrict__ flag,
                                                 bf16* __restrict__ Xc) {
  const int isf = *flag;
  const void* s = (blockIdx.y == 0) ? X0 : (blockIdx.y == 1) ? X1 : X2;
  const size_t vi = (size_t)blockIdx.x * 256 + threadIdx.x;  // float4 index
  bf16* dst = Xc + (size_t)blockIdx.y * XSZ + vi * 4;
  if (isf) {
    const float4 f = ((const float4*)s)[vi];
    bf16x4 o = {(bf16)f.x, (bf16)f.y, (bf16)f.z, (bf16)f.w};
    *(bf16x4*)dst = o;
  } else {
    *(bf16x4*)dst = *(const bf16x4*)((const bf16*)s + vi * 4);
  }
}

__global__ __launch_bounds__(256) void convert_bias(const void* __restrict__ b0,
                                                    const void* __restrict__ b1,
                                                    const void* __restrict__ b2,
                                                    const void* __restrict__ b3,
                                                    const int* __restrict__ flag,
                                                    bf16* __restrict__ bc) {
  const int isf = *flag;
  const int m = blockIdx.x;
  const void* s = (m == 0) ? b0 : (m == 1) ? b1 : (m == 2) ? b2 : b3;
  bf16* dst = bc + m * 1024;
  for (int i = threadIdx.x; i < 1024; i += 256)
    dst[i] = isf ? (bf16)((const float*)s)[i] : ((const bf16*)s)[i];
}

// transpose 4 weight matrices [1024][1024] -> WT4 ([out][in] each), flag-aware read
__global__ __launch_bounds__(256) void transpose4(const void* __restrict__ W0,
                                                  const void* __restrict__ W1,
                                                  const void* __restrict__ W2,
                                                  const void* __restrict__ W3,
                                                  const int* __restrict__ flag,
                                                  bf16* __restrict__ out) {
  __shared__ bf16 t[64][65];
  const int isf = *flag;
  const int mat = blockIdx.z;
  const void* W = (mat == 0) ? W0 : (mat == 1) ? W1 : (mat == 2) ? W2 : W3;
  bf16* o = out + (size_t)mat * MAT;
  const int r0 = blockIdx.y * 64, c0 = blockIdx.x * 64;
  const int tt = threadIdx.x;
#pragma unroll
  for (int e = 0; e < 16; e++) {
    const int idx = tt + e * 256;
    const size_t gi = (size_t)(r0 + (idx >> 6)) * D + c0 + (idx & 63);
    t[idx >> 6][idx & 63] = isf ? (bf16)((const float*)W)[gi] : ((const bf16*)W)[gi];
  }
  __syncthreads();
#pragma unroll
  for (int e = 0; e < 16; e++) {
    const int idx = tt + e * 256;
    const int co = idx >> 6, ro = idx & 63;
    o[(size_t)(c0 + co) * D + r0 + ro] = t[ro][co];
  }
}

// ---------------- GEMM core (m97 pattern) ----------------
DEV void gemm_core(const bf16* __restrict__ A, const bf16* __restrict__ WT,
                   int m0, int n0, bf16* As, bf16* Bs, f32x4 acc[4][4]) {
  const int tid = threadIdx.x;
  const int w = tid >> 6, lane = tid & 63;
  const int ln = lane & 15, qd = lane >> 4;
  const int wr = w >> 1, wc = w & 1;
  const int l8r = lane >> 3, l8c = lane & 7;
  const int swz8 = ((l8c ^ l8r) * 8);

#pragma unroll
  for (int i = 0; i < 4; i++)
#pragma unroll
    for (int j = 0; j < 4; j++) acc[i][j] = (f32x4){0.f, 0.f, 0.f, 0.f};

  for (int k0 = 0; k0 < D; k0 += 64) {
    __syncthreads();
#pragma unroll
    for (int t = 0; t < 4; t++) {
      const int c = w * 4 + t;
      glds16(A + (size_t)(m0 + c * 8 + l8r) * D + k0 + swz8, As + c * 512);
      glds16(WT + (size_t)(n0 + c * 8 + l8r) * D + k0 + swz8, Bs + c * 512);
    }
    __syncthreads();
#pragma unroll
    for (int ks = 0; ks < 2; ks++) {
      bf16x8 af[4], bfr[4];
#pragma unroll
      for (int i = 0; i < 4; i++)
        af[i] = *(const bf16x8*)(As + (wr * 64 + i * 16 + ln) * 64 +
                                 (((ks * 4 + qd) ^ (ln & 7)) * 8));
#pragma unroll
      for (int j = 0; j < 4; j++)
        bfr[j] = *(const bf16x8*)(Bs + (wc * 64 + j * 16 + ln) * 64 +
                                  (((ks * 4 + qd) ^ (ln & 7)) * 8));
#pragma unroll
      for (int i = 0; i < 4; i++)
#pragma unroll
        for (int j = 0; j < 4; j++)
          acc[i][j] = __builtin_amdgcn_mfma_f32_16x16x32_bf16(af[i], bfr[j], acc[i][j], 0, 0, 0);
    }
  }
}

// Fused Q/K/V projection. Q pre-scaled by 0.125 (=1/sqrt(hd), exact in bf16).
__global__ __launch_bounds__(256) void qkv_kernel(
    const bf16* __restrict__ Xc, const bf16* __restrict__ WT4, const bf16* __restrict__ bc,
    bf16* __restrict__ Qb, bf16* __restrict__ Kb, bf16* __restrict__ Vb) {
  __shared__ __align__(16) bf16 As[128 * 64];
  __shared__ __align__(16) bf16 Bs[128 * 64];
  const int mt = blockIdx.x;
  const int nb = blockIdx.y;
  const int mat = nb >> 3;
  const int n0 = (nb & 7) * 128;
  const bf16* A = Xc + (size_t)mat * XSZ;
  const bf16* WT = WT4 + (size_t)mat * MAT;
  const bf16* bias = bc + mat * 1024;

  f32x4 acc[4][4];
  gemm_core(A, WT, mt * 128, n0, As, Bs, acc);

  const int tid = threadIdx.x;
  const int w = tid >> 6, lane = tid & 63;
  const int ln = lane & 15, qd = lane >> 4;
  const int wr = w >> 1, wc = w & 1;
  bf16* dst = (mat == 0) ? Qb : (mat == 1) ? Kb : Vb;
  const float scale = (mat == 0) ? 0.125f : 1.0f;

#pragma unroll
  for (int i = 0; i < 4; i++)
#pragma unroll
    for (int j = 0; j < 4; j++) {
      const int col = n0 + wc * 64 + j * 16 + ln;
      const float bb = (float)bias[col];
      const int h = col >> 6, dd = col & 63;
#pragma unroll
      for (int r = 0; r < 4; r++) {
        const int tok = mt * 128 + wr * 64 + i * 16 + qd * 4 + r;
        const int b = tok >> 11, s = tok & (S_ - 1);
        dst[(size_t)((b * NH + h) * S_ + s) * HD + dd] = (bf16)((acc[i][j][r] + bb) * scale);
      }
    }
}

// V [b,h,s,dd] -> VT [b,h,dd,s]
__global__ __launch_bounds__(256) void transpose_v(const bf16* __restrict__ Vb,
                                                   bf16* __restrict__ VTb) {
  __shared__ bf16 t[64][72];
  const int s0 = blockIdx.x * 64;
  const size_t base = (size_t)blockIdx.y * S_ * HD;
  const int tid = threadIdx.x;
#pragma unroll
  for (int e = 0; e < 16; e++) {
    const int idx = tid + e * 256;
    t[idx >> 6][idx & 63] = Vb[base + (size_t)(s0 + (idx >> 6)) * HD + (idx & 63)];
  }
  __syncthreads();
#pragma unroll
  for (int e = 0; e < 16; e++) {
    const int idx = tid + e * 256;
    const int dd = idx >> 6, sc = idx & 63;
    VTb[base + (size_t)dd * S_ + s0 + sc] = t[sc][dd];
  }
}

// Split-K flash attention. grid (32 bh, 16 qt, 2 split); 4 waves x 32 q-rows.
// 64-key inner chunks keep the live set <=128 VGPR -> 4 blocks/CU resident.
// Writes unnormalized partial O (bf16) + per-row (m,l) (fp32).
__global__ __launch_bounds__(256, 4) void attn_kernel(const bf16* __restrict__ Qb,
                                                      const bf16* __restrict__ Kb,
                                                      const bf16* __restrict__ VTb,
                                                      bf16* __restrict__ Opart,
                                                      float2* __restrict__ ml) {
  __shared__ __align__(16) bf16 P2[128 * 68];  // row stride 68 elems: bank shift 2/row

  const int bh = blockIdx.x;
  const int qt = blockIdx.y;
  const int sp = blockIdx.z;
  const int tid = threadIdx.x;
  const int w = tid >> 6, lane = tid & 63;
  const int ln = lane & 15, qd = lane >> 4;

  const size_t base = (size_t)bh * S_ * HD;
  const int q0 = qt * 128;
  const bf16* Kp = Kb + base;
  const bf16* Vp = VTb + base;
  bf16* Pw = P2 + (w * 32) * 68;  // wave-private 32 rows

  // Q fragments in registers (pre-scaled by 1/8 at projection)
  bf16x8 qf[2][2];
#pragma unroll
  for (int i = 0; i < 2; i++)
#pragma unroll
    for (int t = 0; t < 2; t++)
      qf[i][t] = *(const bf16x8*)(Qb + base + (size_t)(q0 + w * 32 + i * 16 + ln) * HD +
                                  t * 32 + qd * 8);

  f32x4 acc_o[2][4];
#pragma unroll
  for (int i = 0; i < 2; i++)
#pragma unroll
    for (int j = 0; j < 4; j++) acc_o[i][j] = (f32x4){0.f, 0.f, 0.f, 0.f};
  float m_i[2] = {-1e30f, -1e30f}, l_i[2] = {0.f, 0.f};

  const int kbeg = sp * (S_ / 2), kend = kbeg + (S_ / 2);
  for (int k0 = kbeg; k0 < kend; k0 += 64) {
    // S^T = K Q^T over a 64-key chunk: rows=key (4 blocks), cols=q (2 blocks)
    f32x4 st[2][4];
#pragma unroll
    for (int i = 0; i < 2; i++)
#pragma unroll
      for (int j = 0; j < 4; j++) st[i][j] = (f32x4){0.f, 0.f, 0.f, 0.f};
#pragma unroll
    for (int t = 0; t < 2; t++) {
      bf16x8 kf[4];
#pragma unroll
      for (int j = 0; j < 4; j++)
        kf[j] = *(const bf16x8*)(Kp + (size_t)(k0 + j * 16 + ln) * HD + t * 32 + qd * 8);
#pragma unroll
      for (int i = 0; i < 2; i++)
#pragma unroll
        for (int j = 0; j < 4; j++)
          st[i][j] = __builtin_amdgcn_mfma_f32_16x16x32_bf16(kf[j], qf[i][t], st[i][j], 0, 0, 0);
    }

    // online softmax; lane owns q-column i*16+ln
#pragma unroll
    for (int i = 0; i < 2; i++) {
      float mx = -1e30f;
#pragma unroll
      for (int j = 0; j < 4; j++)
#pragma unroll
        for (int r = 0; r < 4; r++) mx = fmaxf(mx, st[i][j][r]);
      mx = fmaxf(mx, __shfl_xor(mx, 16));
      mx = fmaxf(mx, __shfl_xor(mx, 32));
      const float mnew = fmaxf(m_i[i], mx);
      const float alpha = __expf(m_i[i] - mnew);
      m_i[i] = mnew;
      float rs = 0.f;
#pragma unroll
      for (int j = 0; j < 4; j++)
#pragma unroll
        for (int r = 0; r < 4; r++) {
          const float p = __expf(st[i][j][r] - mnew);
          st[i][j][r] = p;
          rs += p;
        }
      rs += __shfl_xor(rs, 16);
      rs += __shfl_xor(rs, 32);
      l_i[i] = l_i[i] * alpha + rs;

      // P rows: lane's 4 consecutive keys -> packed b64 (8 chunks, XOR by ln&7)
      {
        bf16* pr = Pw + (i * 16 + ln) * 68;
#pragma unroll
        for (int j = 0; j < 4; j++) {
          bf16x4 pv;
#pragma unroll
          for (int r = 0; r < 4; r++) pv[r] = (bf16)st[i][j][r];
          *(bf16x4*)(pr + (((j * 2 + (qd >> 1)) ^ (ln & 7)) * 8) + (qd & 1) * 4) = pv;
        }
      }

      // rescale O accumulator (C-layout rows q = i*16 + qd*4 + r)
#pragma unroll
      for (int r = 0; r < 4; r++) {
        const float ar = __shfl(alpha, qd * 4 + r);
#pragma unroll
        for (int jn = 0; jn < 4; jn++) acc_o[i][jn][r] *= ar;
      }
    }

    // O += P V : A = P from LDS (b128), B = V^T direct from global
#pragma unroll
    for (int t = 0; t < 2; t++) {
      bf16x8 vf[4], pf[2];
#pragma unroll
      for (int jn = 0; jn < 4; jn++)
        vf[jn] = *(const bf16x8*)(Vp + (size_t)(jn * 16 + ln) * S_ + k0 + t * 32 + qd * 8);
#pragma unroll
      for (int i = 0; i < 2; i++)
        pf[i] = *(const bf16x8*)(Pw + (i * 16 + ln) * 68 + (((t * 4 + qd) ^ (ln & 7)) * 8));
#pragma unroll
      for (int i = 0; i < 2; i++)
#pragma unroll
        for (int jn = 0; jn < 4; jn++)
          acc_o[i][jn] = __builtin_amdgcn_mfma_f32_16x16x32_bf16(pf[i], vf[jn], acc_o[i][jn], 0, 0, 0);
    }
  }

  // partial epilogue: unnormalized O + (m,l)
  const size_t obase = ((size_t)sp * 32 + bh) * (size_t)S_ * HD;
#pragma unroll
  for (int i = 0; i < 2; i++) {
#pragma unroll
    for (int r = 0; r < 4; r++) {
      const int q = q0 + w * 32 + i * 16 + qd * 4 + r;
#pragma unroll
      for (int jn = 0; jn < 4; jn++)
        Opart[obase + (size_t)q * HD + jn * 16 + ln] = (bf16)acc_o[i][jn][r];
    }
    if (qd == 0) {
      const int q = q0 + w * 32 + i * 16 + ln;
      ml[((size_t)sp * 32 + bh) * S_ + q] = make_float2(m_i[i], l_i[i]);
    }
  }
}

// merge 2 split partials -> Ob [token][h*64+dd]
__global__ __launch_bounds__(256) void merge_k(const bf16* __restrict__ Opart,
                                               const float2* __restrict__ ml,
                                               bf16* __restrict__ Ob) {
  const int gid = blockIdx.x * 256 + threadIdx.x;  // 4M threads
  const int dd = gid & 63;
  const int row = gid >> 6;  // bh*2048 + q
  const int bh = row >> 11, q = row & 2047;
  const float2 ml0 = ml[row];
  const float2 ml1 = ml[32 * S_ + row];
  const float m = fmaxf(ml0.x, ml1.x);
  const float a0 = __expf(ml0.x - m), a1 = __expf(ml1.x - m);
  const float inv = 1.0f / (a0 * ml0.y + a1 * ml1.y);
  const float o0 = (float)Opart[(size_t)row * HD + dd];
  const float o1 = (float)Opart[((size_t)32 * S_ + row) * HD + dd];
  const int b = bh >> 4, h = bh & 15;
  Ob[((size_t)(b * S_ + q)) * D + h * HD + dd] = (bf16)((a0 * o0 + a1 * o1) * inv);
}

// final projection: out = O @ Wo + bo; output dtype per flag
__global__ __launch_bounds__(256) void oproj_kernel(const bf16* __restrict__ Ob,
                                                    const bf16* __restrict__ WoT,
                                                    const bf16* __restrict__ bo,
                                                    const int* __restrict__ flag,
                                                    void* __restrict__ outv) {
  __shared__ __align__(16) bf16 As[128 * 64];
  __shared__ __align__(16) bf16 Bs[128 * 64];
  const int isf = *flag;
  const int mt = blockIdx.x, nb = blockIdx.y;
  f32x4 acc[4][4];
  gemm_core(Ob, WoT, mt * 128, nb * 128, As, Bs, acc);
  const int tid = threadIdx.x;
  const int w = tid >> 6, lane = tid & 63;
  const int ln = lane & 15, qd = lane >> 4;
  const int wr = w >> 1, wc = w & 1;
#pragma unroll
  for (int i = 0; i < 4; i++)
#pragma unroll
    for (int j = 0; j < 4; j++) {
      const int col = nb * 128 + wc * 64 + j * 16 + ln;
      const float bb = (float)bo[col];
#pragma unroll
      for (int r = 0; r < 4; r++) {
        const int tok = mt * 128 + wr * 64 + i * 16 + qd * 4 + r;
        const float v = acc[i][j][r] + bb;
        const size_t oi = (size_t)tok * D + col;
        if (isf) ((float*)outv)[oi] = v;
        else ((bf16*)outv)[oi] = (bf16)v;
      }
    }
}

extern "C" void kernel_launch(void* const* d_in, const int* in_sizes, int n_in,
                              void* d_out, int out_size, void* d_ws, size_t ws_size,
                              hipStream_t stream) {
  int* flag = (int*)d_ws;
  bf16* ws = (bf16*)d_ws + 2048;  // 4 KB header

  bf16* WT4 = ws;                       // 4*MAT (8 MB); mats 0-2 dead after qkv
  bf16* Xc  = WT4 + 4 * MAT;            // 3*XSZ (24 MB); dead after qkv
  bf16* bc  = Xc + 3 * XSZ;             // 4096
  bf16* Qb  = bc + 4096;                // XSZ each
  bf16* Kb  = Qb + XSZ;
  bf16* VTb = Kb + XSZ;
  bf16* Ob  = VTb + XSZ;
  bf16* Vb  = Ob;                       // alias: consumed by transpose_v before merge writes Ob
  // split-K partials alias the dead Xc region (17 MB <= 24 MB)
  bf16*   Opart = Xc;                              // 2*32*2048*64 bf16 = 16 MB
  float2* mlbuf = (float2*)(Xc + 2 * 32 * (size_t)S_ * HD);  // 1 MB

  detect_k<<<1, 256, 0, stream>>>((const unsigned short*)d_in[3], flag);
  convert_x<<<dim3(4096, 3), 256, 0, stream>>>(d_in[0], d_in[1], d_in[2], flag, Xc);
  convert_bias<<<4, 256, 0, stream>>>(d_in[4], d_in[6], d_in[8], d_in[10], flag, bc);
  transpose4<<<dim3(16, 16, 4), 256, 0, stream>>>(d_in[3], d_in[5], d_in[7], d_in[9], flag, WT4);
  qkv_kernel<<<dim3(32, 24), 256, 0, stream>>>(Xc, WT4, bc, Qb, Kb, Vb);
  transpose_v<<<dim3(32, 32), 256, 0, stream>>>(Vb, VTb);
  attn_kernel<<<dim3(32, 16, 2), 256, 0, stream>>>(Qb, Kb, VTb, Opart, mlbuf);
  merge_k<<<16384, 256, 0, stream>>>(Opart, mlbuf, Ob);
  oproj_kernel<<<dim3(32, 8), 256, 0, stream>>>(Ob, WT4 + 3 * MAT, bc + 3 * 1024, flag, d_out);
}

// Round 5
// 291.470 us; speedup vs baseline: 1.1632x; 1.1632x over previous
//
#include <hip/hip_runtime.h>

// MHA fwd: B=2, S=2048, d=1024, H=16, hd=64. fp32 accum, bf16 MFMA compute.
// Split-K flash attention with MFMA-fragment-native (tiled) K/Q/V layouts:
// every fragment load is one fully-coalesced 1KB dwordx4 (fixes TA-transaction bound).

typedef __bf16 bf16;
typedef __bf16 bf16x4 __attribute__((ext_vector_type(4)));
typedef __bf16 bf16x8 __attribute__((ext_vector_type(8)));
typedef float f32x4 __attribute__((ext_vector_type(4)));

#define DEV static __device__ __forceinline__

constexpr int D = 1024;
constexpr int NH = 16;
constexpr int HD = 64;
constexpr int B_ = 2;
constexpr int S_ = 2048;
constexpr size_t MAT = (size_t)D * D;        // 1,048,576
constexpr size_t XSZ = (size_t)B_ * S_ * D;  // 4,194,304

DEV void glds16(const bf16* g, bf16* l) {
  __builtin_amdgcn_global_load_lds(
      (__attribute__((address_space(1))) void*)g,
      (__attribute__((address_space(3))) void*)l, 16, 0, 0);
}

// ---------------- dtype detection ----------------
__global__ __launch_bounds__(256) void detect_k(const unsigned short* __restrict__ w,
                                                int* __restrict__ flag) {
  __shared__ int sbuf[256];
  const int tid = threadIdx.x;
  int cnt = 0;
  for (int i = tid; i < 8192; i += 256) {
    const unsigned e = (w[i] >> 7) & 0xFF;
    if (e >= 0x90) cnt++;
  }
  sbuf[tid] = cnt;
  __syncthreads();
  for (int s = 128; s > 0; s >>= 1) {
    if (tid < s) sbuf[tid] += sbuf[tid + s];
    __syncthreads();
  }
  if (tid == 0) flag[0] = (sbuf[0] > 32) ? 1 : 0;
}

// ---------------- input conversion (coalesced float4) ----------------
__global__ __launch_bounds__(256) void convert_x(const void* __restrict__ X0,
                                                 const void* __restrict__ X1,
                                                 const void* __restrict__ X2,
                                                 const int* __restrict__ flag,
                                                 bf16* __restrict__ Xc) {
  const int isf = *flag;
  const void* s = (blockIdx.y == 0) ? X0 : (blockIdx.y == 1) ? X1 : X2;
  const size_t vi = (size_t)blockIdx.x * 256 + threadIdx.x;  // float4 index
  bf16* dst = Xc + (size_t)blockIdx.y * XSZ + vi * 4;
  if (isf) {
    const float4 f = ((const float4*)s)[vi];
    bf16x4 o = {(bf16)f.x, (bf16)f.y, (bf16)f.z, (bf16)f.w};
    *(bf16x4*)dst = o;
  } else {
    *(bf16x4*)dst = *(const bf16x4*)((const bf16*)s + vi * 4);
  }
}

__global__ __launch_bounds__(256) void convert_bias(const void* __restrict__ b0,
                                                    const void* __restrict__ b1,
                                                    const void* __restrict__ b2,
                                                    const void* __restrict__ b3,
                                                    const int* __restrict__ flag,
                                                    bf16* __restrict__ bc) {
  const int isf = *flag;
  const int m = blockIdx.x;
  const void* s = (m == 0) ? b0 : (m == 1) ? b1 : (m == 2) ? b2 : b3;
  bf16* dst = bc + m * 1024;
  for (int i = threadIdx.x; i < 1024; i += 256)
    dst[i] = isf ? (bf16)((const float*)s)[i] : ((const bf16*)s)[i];
}

// transpose 4 weight matrices [1024][1024] -> WT4 ([out][in] each), flag-aware read
__global__ __launch_bounds__(256) void transpose4(const void* __restrict__ W0,
                                                  const void* __restrict__ W1,
                                                  const void* __restrict__ W2,
                                                  const void* __restrict__ W3,
                                                  const int* __restrict__ flag,
                                                  bf16* __restrict__ out) {
  __shared__ bf16 t[64][65];
  const int isf = *flag;
  const int mat = blockIdx.z;
  const void* W = (mat == 0) ? W0 : (mat == 1) ? W1 : (mat == 2) ? W2 : W3;
  bf16* o = out + (size_t)mat * MAT;
  const int r0 = blockIdx.y * 64, c0 = blockIdx.x * 64;
  const int tt = threadIdx.x;
#pragma unroll
  for (int e = 0; e < 16; e++) {
    const int idx = tt + e * 256;
    const size_t gi = (size_t)(r0 + (idx >> 6)) * D + c0 + (idx & 63);
    t[idx >> 6][idx & 63] = isf ? (bf16)((const float*)W)[gi] : ((const bf16*)W)[gi];
  }
  __syncthreads();
#pragma unroll
  for (int e = 0; e < 16; e++) {
    const int idx = tt + e * 256;
    const int co = idx >> 6, ro = idx & 63;
    o[(size_t)(c0 + co) * D + r0 + ro] = t[ro][co];
  }
}

// ---------------- GEMM core (m97 pattern) ----------------
DEV void gemm_core(const bf16* __restrict__ A, const bf16* __restrict__ WT,
                   int m0, int n0, bf16* As, bf16* Bs, f32x4 acc[4][4]) {
  const int tid = threadIdx.x;
  const int w = tid >> 6, lane = tid & 63;
  const int ln = lane & 15, qd = lane >> 4;
  const int wr = w >> 1, wc = w & 1;
  const int l8r = lane >> 3, l8c = lane & 7;
  const int swz8 = ((l8c ^ l8r) * 8);

#pragma unroll
  for (int i = 0; i < 4; i++)
#pragma unroll
    for (int j = 0; j < 4; j++) acc[i][j] = (f32x4){0.f, 0.f, 0.f, 0.f};

  for (int k0 = 0; k0 < D; k0 += 64) {
    __syncthreads();
#pragma unroll
    for (int t = 0; t < 4; t++) {
      const int c = w * 4 + t;
      glds16(A + (size_t)(m0 + c * 8 + l8r) * D + k0 + swz8, As + c * 512);
      glds16(WT + (size_t)(n0 + c * 8 + l8r) * D + k0 + swz8, Bs + c * 512);
    }
    __syncthreads();
#pragma unroll
    for (int ks = 0; ks < 2; ks++) {
      bf16x8 af[4], bfr[4];
#pragma unroll
      for (int i = 0; i < 4; i++)
        af[i] = *(const bf16x8*)(As + (wr * 64 + i * 16 + ln) * 64 +
                                 (((ks * 4 + qd) ^ (ln & 7)) * 8));
#pragma unroll
      for (int j = 0; j < 4; j++)
        bfr[j] = *(const bf16x8*)(Bs + (wc * 64 + j * 16 + ln) * 64 +
                                  (((ks * 4 + qd) ^ (ln & 7)) * 8));
#pragma unroll
      for (int i = 0; i < 4; i++)
#pragma unroll
        for (int j = 0; j < 4; j++)
          acc[i][j] = __builtin_amdgcn_mfma_f32_16x16x32_bf16(af[i], bfr[j], acc[i][j], 0, 0, 0);
    }
  }
}

// Fused Q/K/V projection. Q pre-scaled by 0.125 (=1/sqrt(hd), exact in bf16).
// Q,K written in A-fragment-tiled layout: per (b,h): [(s>>4)][(dd>>3)][s&15][dd&7]
// V written in B-fragment-tiled layout:   per (b,h): [(dd>>4)][(s>>5)][(s>>3)&3][dd&15][s&7]
__global__ __launch_bounds__(256) void qkv_kernel(
    const bf16* __restrict__ Xc, const bf16* __restrict__ WT4, const bf16* __restrict__ bc,
    bf16* __restrict__ Qb, bf16* __restrict__ Kb, bf16* __restrict__ Vb) {
  __shared__ __align__(16) bf16 As[128 * 64];
  __shared__ __align__(16) bf16 Bs[128 * 64];
  const int mt = blockIdx.x;
  const int nb = blockIdx.y;
  const int mat = nb >> 3;
  const int n0 = (nb & 7) * 128;
  const bf16* A = Xc + (size_t)mat * XSZ;
  const bf16* WT = WT4 + (size_t)mat * MAT;
  const bf16* bias = bc + mat * 1024;

  f32x4 acc[4][4];
  gemm_core(A, WT, mt * 128, n0, As, Bs, acc);

  const int tid = threadIdx.x;
  const int w = tid >> 6, lane = tid & 63;
  const int ln = lane & 15, qd = lane >> 4;
  const int wr = w >> 1, wc = w & 1;
  bf16* dst = (mat == 0) ? Qb : (mat == 1) ? Kb : Vb;
  const float scale = (mat == 0) ? 0.125f : 1.0f;

#pragma unroll
  for (int i = 0; i < 4; i++)
#pragma unroll
    for (int j = 0; j < 4; j++) {
      const int col = n0 + wc * 64 + j * 16 + ln;
      const float bb = (float)bias[col];
      const int h = col >> 6, dd = col & 63;
      const int tok0 = mt * 128 + wr * 64 + i * 16 + qd * 4;  // 4 consecutive tokens
      const int b = tok0 >> 11, s0 = tok0 & (S_ - 1);
      bf16* base = dst + (size_t)(b * NH + h) * S_ * HD;
      if (mat == 2) {
        // V tiled: 4 consecutive s -> contiguous 8B run
        bf16x4 pv;
#pragma unroll
        for (int r = 0; r < 4; r++) pv[r] = (bf16)(acc[i][j][r] + bb);
        const size_t off = ((size_t)((dd >> 4) * (S_ >> 5) + (s0 >> 5))) * 512 +
                           ((s0 >> 3) & 3) * 128 + (dd & 15) * 8 + (s0 & 7);
        *(bf16x4*)(base + off) = pv;
      } else {
#pragma unroll
        for (int r = 0; r < 4; r++) {
          const int s = s0 + r;
          const size_t off = ((size_t)(s >> 4)) * 1024 + (dd >> 3) * 128 + (s & 15) * 8 + (dd & 7);
          base[off] = (bf16)((acc[i][j][r] + bb) * scale);
        }
      }
    }
}

// Split-K flash attention. grid (32 bh, 16 qt, 2 split); 4 waves x 32 q-rows.
// All K/Q/V fragment loads are single fully-coalesced 1KB dwordx4 from tiled layouts.
// Writes unnormalized partial O (bf16) + per-row (m,l) (fp32).
__global__ __launch_bounds__(256, 3) void attn_kernel(const bf16* __restrict__ Qb,
                                                      const bf16* __restrict__ Kb,
                                                      const bf16* __restrict__ Vb,
                                                      bf16* __restrict__ Opart,
                                                      float2* __restrict__ ml) {
  __shared__ __align__(16) bf16 P2[128 * 136];  // [q][128 keys], row stride 136

  const int bh = blockIdx.x;
  const int qt = blockIdx.y;
  const int sp = blockIdx.z;
  const int tid = threadIdx.x;
  const int w = tid >> 6, lane = tid & 63;
  const int ln = lane & 15, qd = lane >> 4;

  const size_t base = (size_t)bh * S_ * HD;
  const int q0 = qt * 128;
  const bf16* Kp = Kb + base;
  const bf16* Vp = Vb + base;
  const bf16* Qp = Qb + base;
  bf16* Pw = P2 + (w * 32) * 136;  // wave-private 32 rows

  // Q fragments (pre-scaled by 1/8). Tiled: ((q>>4)*8 + ddchunk)*128 + (q&15)*8
  bf16x8 qf[2][2];
#pragma unroll
  for (int i = 0; i < 2; i++)
#pragma unroll
    for (int t = 0; t < 2; t++)
      qf[i][t] = *(const bf16x8*)(Qp + (size_t)(qt * 8 + w * 2 + i) * 1024 +
                                  (t * 4 + qd) * 128 + ln * 8);

  f32x4 acc_o[2][4];
#pragma unroll
  for (int i = 0; i < 2; i++)
#pragma unroll
    for (int j = 0; j < 4; j++) acc_o[i][j] = (f32x4){0.f, 0.f, 0.f, 0.f};
  float m_i[2] = {-1e30f, -1e30f}, l_i[2] = {0.f, 0.f};

  const int kbeg = sp * (S_ / 2), kend = kbeg + (S_ / 2);
  for (int k0 = kbeg; k0 < kend; k0 += 128) {
    // S^T = K Q^T over a 128-key chunk: rows=key (8 blocks), cols=q (2 blocks)
    f32x4 st[2][8];
#pragma unroll
    for (int i = 0; i < 2; i++)
#pragma unroll
      for (int j = 0; j < 8; j++) st[i][j] = (f32x4){0.f, 0.f, 0.f, 0.f};
#pragma unroll
    for (int t = 0; t < 2; t++) {
      bf16x8 kf[8];
#pragma unroll
      for (int j = 0; j < 8; j++)
        kf[j] = *(const bf16x8*)(Kp + (size_t)((k0 >> 4) + j) * 1024 +
                                 (t * 4 + qd) * 128 + ln * 8);
#pragma unroll
      for (int i = 0; i < 2; i++)
#pragma unroll
        for (int j = 0; j < 8; j++)
          st[i][j] = __builtin_amdgcn_mfma_f32_16x16x32_bf16(kf[j], qf[i][t], st[i][j], 0, 0, 0);
    }

    // online softmax; lane owns q-column i*16+ln
#pragma unroll
    for (int i = 0; i < 2; i++) {
      float mx = -1e30f;
#pragma unroll
      for (int j = 0; j < 8; j++)
#pragma unroll
        for (int r = 0; r < 4; r++) mx = fmaxf(mx, st[i][j][r]);
      mx = fmaxf(mx, __shfl_xor(mx, 16));
      mx = fmaxf(mx, __shfl_xor(mx, 32));
      const float mnew = fmaxf(m_i[i], mx);
      const float alpha = __expf(m_i[i] - mnew);
      m_i[i] = mnew;
      float rs = 0.f;
#pragma unroll
      for (int j = 0; j < 8; j++)
#pragma unroll
        for (int r = 0; r < 4; r++) {
          const float p = __expf(st[i][j][r] - mnew);
          st[i][j][r] = p;
          rs += p;
        }
      rs += __shfl_xor(rs, 16);
      rs += __shfl_xor(rs, 32);
      l_i[i] = l_i[i] * alpha + rs;

      // P rows: lane's 4 consecutive keys -> b64; 16 chunks XOR-swizzled by ln&7
      {
        bf16* pr = Pw + (i * 16 + ln) * 136;
#pragma unroll
        for (int j = 0; j < 8; j++) {
          bf16x4 pv;
#pragma unroll
          for (int r = 0; r < 4; r++) pv[r] = (bf16)st[i][j][r];
          const int c0 = j * 2 + (qd >> 1);
          *(bf16x4*)(pr + ((c0 ^ (ln & 7)) * 8) + (qd & 1) * 4) = pv;
        }
      }

      // rescale O accumulator (C-layout rows q = i*16 + qd*4 + r)
#pragma unroll
      for (int r = 0; r < 4; r++) {
        const float ar = __shfl(alpha, qd * 4 + r);
#pragma unroll
        for (int jn = 0; jn < 4; jn++) acc_o[i][jn][r] *= ar;
      }
    }

    // O += P V : A = P from LDS (b128), B = V tiled direct from global (1KB coalesced)
#pragma unroll
    for (int t = 0; t < 4; t++) {
      bf16x8 vf[4], pf[2];
#pragma unroll
      for (int jn = 0; jn < 4; jn++)
        vf[jn] = *(const bf16x8*)(Vp + (size_t)(jn * (S_ >> 5) + (k0 >> 5) + t) * 512 +
                                  qd * 128 + ln * 8);
#pragma unroll
      for (int i = 0; i < 2; i++)
        pf[i] = *(const bf16x8*)(Pw + (i * 16 + ln) * 136 + (((t * 4 + qd) ^ (ln & 7)) * 8));
#pragma unroll
      for (int i = 0; i < 2; i++)
#pragma unroll
        for (int jn = 0; jn < 4; jn++)
          acc_o[i][jn] = __builtin_amdgcn_mfma_f32_16x16x32_bf16(pf[i], vf[jn], acc_o[i][jn], 0, 0, 0);
    }
  }

  // partial epilogue: unnormalized O + (m,l)
  const size_t obase = ((size_t)sp * 32 + bh) * (size_t)S_ * HD;
#pragma unroll
  for (int i = 0; i < 2; i++) {
#pragma unroll
    for (int r = 0; r < 4; r++) {
      const int q = q0 + w * 32 + i * 16 + qd * 4 + r;
#pragma unroll
      for (int jn = 0; jn < 4; jn++)
        Opart[obase + (size_t)q * HD + jn * 16 + ln] = (bf16)acc_o[i][jn][r];
    }
    if (qd == 0) {
      const int q = q0 + w * 32 + i * 16 + ln;
      ml[((size_t)sp * 32 + bh) * S_ + q] = make_float2(m_i[i], l_i[i]);
    }
  }
}

// merge 2 split partials -> Ob [token][h*64+dd]
__global__ __launch_bounds__(256) void merge_k(const bf16* __restrict__ Opart,
                                               const float2* __restrict__ ml,
                                               bf16* __restrict__ Ob) {
  const int gid = blockIdx.x * 256 + threadIdx.x;  // 4M threads
  const int dd = gid & 63;
  const int row = gid >> 6;  // bh*2048 + q
  const int bh = row >> 11, q = row & 2047;
  const float2 ml0 = ml[row];
  const float2 ml1 = ml[32 * S_ + row];
  const float m = fmaxf(ml0.x, ml1.x);
  const float a0 = __expf(ml0.x - m), a1 = __expf(ml1.x - m);
  const float inv = 1.0f / (a0 * ml0.y + a1 * ml1.y);
  const float o0 = (float)Opart[(size_t)row * HD + dd];
  const float o1 = (float)Opart[((size_t)32 * S_ + row) * HD + dd];
  const int b = bh >> 4, h = bh & 15;
  Ob[((size_t)(b * S_ + q)) * D + h * HD + dd] = (bf16)((a0 * o0 + a1 * o1) * inv);
}

// final projection: out = O @ Wo + bo; output dtype per flag
__global__ __launch_bounds__(256) void oproj_kernel(const bf16* __restrict__ Ob,
                                                    const bf16* __restrict__ WoT,
                                                    const bf16* __restrict__ bo,
                                                    const int* __restrict__ flag,
                                                    void* __restrict__ outv) {
  __shared__ __align__(16) bf16 As[128 * 64];
  __shared__ __align__(16) bf16 Bs[128 * 64];
  const int isf = *flag;
  const int mt = blockIdx.x, nb = blockIdx.y;
  f32x4 acc[4][4];
  gemm_core(Ob, WoT, mt * 128, nb * 128, As, Bs, acc);
  const int tid = threadIdx.x;
  const int w = tid >> 6, lane = tid & 63;
  const int ln = lane & 15, qd = lane >> 4;
  const int wr = w >> 1, wc = w & 1;
#pragma unroll
  for (int i = 0; i < 4; i++)
#pragma unroll
    for (int j = 0; j < 4; j++) {
      const int col = nb * 128 + wc * 64 + j * 16 + ln;
      const float bb = (float)bo[col];
#pragma unroll
      for (int r = 0; r < 4; r++) {
        const int tok = mt * 128 + wr * 64 + i * 16 + qd * 4 + r;
        const float v = acc[i][j][r] + bb;
        const size_t oi = (size_t)tok * D + col;
        if (isf) ((float*)outv)[oi] = v;
        else ((bf16*)outv)[oi] = (bf16)v;
      }
    }
}

extern "C" void kernel_launch(void* const* d_in, const int* in_sizes, int n_in,
                              void* d_out, int out_size, void* d_ws, size_t ws_size,
                              hipStream_t stream) {
  int* flag = (int*)d_ws;
  bf16* ws = (bf16*)d_ws + 2048;  // 4 KB header

  bf16* WT4 = ws;                       // 4*MAT (8 MB)
  bf16* Xc  = WT4 + 4 * MAT;            // 3*XSZ (24 MB); dead after qkv
  bf16* bc  = Xc + 3 * XSZ;             // 4096
  bf16* Qb  = bc + 4096;                // XSZ each (tiled layouts)
  bf16* Kb  = Qb + XSZ;
  bf16* Vb  = Kb + XSZ;
  bf16* Ob  = Vb + XSZ;
  // split-K partials alias the dead Xc region (17 MB <= 24 MB)
  bf16*   Opart = Xc;                                        // 16 MB
  float2* mlbuf = (float2*)(Xc + 2 * 32 * (size_t)S_ * HD);  // 1 MB

  detect_k<<<1, 256, 0, stream>>>((const unsigned short*)d_in[3], flag);
  convert_x<<<dim3(4096, 3), 256, 0, stream>>>(d_in[0], d_in[1], d_in[2], flag, Xc);
  convert_bias<<<4, 256, 0, stream>>>(d_in[4], d_in[6], d_in[8], d_in[10], flag, bc);
  transpose4<<<dim3(16, 16, 4), 256, 0, stream>>>(d_in[3], d_in[5], d_in[7], d_in[9], flag, WT4);
  qkv_kernel<<<dim3(32, 24), 256, 0, stream>>>(Xc, WT4, bc, Qb, Kb, Vb);
  attn_kernel<<<dim3(32, 16, 2), 256, 0, stream>>>(Qb, Kb, Vb, Opart, mlbuf);
  merge_k<<<16384, 256, 0, stream>>>(Opart, mlbuf, Ob);
  oproj_kernel<<<dim3(32, 8), 256, 0, stream>>>(Ob, WT4 + 3 * MAT, bc + 3 * 1024, flag, d_out);
}